// Round 2
// baseline (472.357 us; speedup 1.0000x reference)
//
#include <hip/hip_runtime.h>

// Edge_cycle fused block, bf16-MFMA, round 6.
//   Round 6: WEIGHTS IN REGISTERS. All B-fragments (5 cycle layers / 2 edge
//   layers) preloaded once per block BEFORE the gather -- their global-load
//   latency overlaps the gather loads, and every inter-barrier layer becomes
//   pure LDS+MFMA (no exposed global latency 5x per tile). Layer loops are
//   mt-outer so only one 16-VGPR afr set is live (weights take 128 VGPRs).
//   cycle6 tile doubled to R=96 (MT=6) for 2x MFMA per barrier interval.
//   Segsum phase vectorized to paired-column u32.
// d_out layout: [edge_out NE*64][out5][out6]; cycle_out = d_out + NE*64.

#define LP 136   // LDS row pitch in bf16 units (128+8: 16B-aligned, 2-way-free banks)

typedef __attribute__((ext_vector_type(8))) short bhalf8;
typedef __attribute__((ext_vector_type(4))) float f32x4;

__device__ __forceinline__ unsigned short f2bf(float f) {
    unsigned u = __builtin_bit_cast(unsigned, f);
    u += 0x7fffu + ((u >> 16) & 1u);          // RNE
    return (unsigned short)(u >> 16);
}
__device__ __forceinline__ float bf2f(unsigned short s) {
    unsigned u = ((unsigned)s) << 16;
    return __builtin_bit_cast(float, u);
}
__device__ __forceinline__ void store4bf(unsigned short* p, float4 v) {
    uint2 u;
    u.x = (unsigned)f2bf(v.x) | ((unsigned)f2bf(v.y) << 16);
    u.y = (unsigned)f2bf(v.z) | ((unsigned)f2bf(v.w) << 16);
    *(uint2*)p = u;
}

// ---------------- prep kernels (2 launches total) -----------------------------
// blocks 0-63:W1  64-95:W2  96-159:Wc2  160-191:Wc3  192-255:We1  256-287:We2
__global__ void tcast_all(const float* __restrict__ W1,  const float* __restrict__ W2,
                          const float* __restrict__ Wc2, const float* __restrict__ Wc3,
                          const float* __restrict__ We1, const float* __restrict__ We2,
                          unsigned short* W1T, unsigned short* W2T,
                          unsigned short* Wc2T, unsigned short* Wc3T,
                          unsigned short* We1T, unsigned short* We2T) {
    int b = blockIdx.x;
    const float* W; unsigned short* WT; int logN, i0;
    if      (b < 64)  { W = W1;  WT = W1T;  logN = 7; i0 = b; }
    else if (b < 96)  { W = W2;  WT = W2T;  logN = 6; i0 = b - 64; }
    else if (b < 160) { W = Wc2; WT = Wc2T; logN = 7; i0 = b - 96; }
    else if (b < 192) { W = Wc3; WT = Wc3T; logN = 6; i0 = b - 160; }
    else if (b < 256) { W = We1; WT = We1T; logN = 7; i0 = b - 192; }
    else              { W = We2; WT = We2T; logN = 6; i0 = b - 256; }
    int i = i0 * 256 + threadIdx.x;
    int k = i >> logN;
    int n = i & ((1 << logN) - 1);
    WT[n * 128 + k] = f2bf(W[i]);
}

// blocks 0-127: WeffT5 row k=b; 128-255: WeffT6; 256: beff5; 257: beff6
__global__ void weff_all(const float* __restrict__ Wc1,
                         const float* __restrict__ Wid5, const float* __restrict__ Wsum5,
                         const float* __restrict__ Wid6, const float* __restrict__ Wsum6,
                         const float* __restrict__ bab5, const float* __restrict__ bab6,
                         const float* __restrict__ bc1,
                         unsigned short* WeffT5, unsigned short* WeffT6,
                         float* beff5, float* beff6) {
    int b = blockIdx.x, n = threadIdx.x;
    if (b < 256) {
        int k = b & 127;
        const float* Wid  = (b < 128) ? Wid5  : Wid6;
        const float* Wsum = (b < 128) ? Wsum5 : Wsum6;
        unsigned short* WT = (b < 128) ? WeffT5 : WeffT6;
        const float* Ws = (k < 64) ? (Wid + (size_t)k * 256) : (Wsum + (size_t)(k - 64) * 256);
        float v = Wc1[k * 128 + n];
        for (int j = 0; j < 256; ++j) v = fmaf(Ws[j], Wc1[(128 + j) * 128 + n], v);
        WT[n * 128 + k] = f2bf(v);
    } else {
        const float* bab = (b == 256) ? bab5 : bab6;
        float* beff = (b == 256) ? beff5 : beff6;
        float v = bc1[n];
        for (int j = 0; j < 256; ++j) v = fmaf(bab[j], Wc1[(128 + j) * 128 + n], v);
        beff[n] = v;
    }
}

// ---------------- weight preload into registers -------------------------------
__device__ __forceinline__ void loadW2(bhalf8 (&bfr)[2][4], const unsigned short* __restrict__ WT,
                                       int m16, int q, int w) {
    #pragma unroll
    for (int g = 0; g < 2; ++g) {
        const int ntg = w + g * 4;
        #pragma unroll
        for (int kc = 0; kc < 4; ++kc)
            bfr[g][kc] = *(const bhalf8*)&WT[(size_t)(ntg * 16 + m16) * 128 + kc * 32 + q * 8];
    }
}
__device__ __forceinline__ void loadW1(bhalf8 (&bfr)[4], const unsigned short* __restrict__ WT,
                                       int m16, int q, int w) {
    #pragma unroll
    for (int kc = 0; kc < 4; ++kc)
        bfr[kc] = *(const bhalf8*)&WT[(size_t)(w * 16 + m16) * 128 + kc * 32 + q * 8];
}

// ---------------- MFMA layers: weights from registers, A from LDS -------------
// Swapped-operand form: mfma(bfr, afr) = (x@W)^T fragment; lane holds
// x_row = m16 (+mt*16), n = ntg*16 + q*4 + r  (4 consecutive cols -> packed store).
template<int MT, bool RELU>
__device__ __forceinline__ void layerR2(const unsigned short* src, unsigned short* dst,
                                        const bhalf8 (&bfr)[2][4],
                                        const float* __restrict__ bias,
                                        int m16, int q, int w) {
    float4 bb[2];
    #pragma unroll
    for (int g = 0; g < 2; ++g) bb[g] = *(const float4*)&bias[(w + g * 4) * 16 + q * 4];
    #pragma unroll
    for (int mt = 0; mt < MT; ++mt) {
        bhalf8 afr[4];
        #pragma unroll
        for (int kc = 0; kc < 4; ++kc)
            afr[kc] = *(const bhalf8*)&src[(mt * 16 + m16) * LP + kc * 32 + q * 8];
        #pragma unroll
        for (int g = 0; g < 2; ++g) {
            f32x4 acc = {bb[g].x, bb[g].y, bb[g].z, bb[g].w};
            #pragma unroll
            for (int kc = 0; kc < 4; ++kc)
                acc = __builtin_amdgcn_mfma_f32_16x16x32_bf16(bfr[g][kc], afr[kc], acc, 0, 0, 0);
            float v0 = acc[0], v1 = acc[1], v2 = acc[2], v3 = acc[3];
            if (RELU) {
                v0 = fmaxf(v0, 0.f); v1 = fmaxf(v1, 0.f);
                v2 = fmaxf(v2, 0.f); v3 = fmaxf(v3, 0.f);
            }
            uint2 u;
            u.x = (unsigned)f2bf(v0) | ((unsigned)f2bf(v1) << 16);
            u.y = (unsigned)f2bf(v2) | ((unsigned)f2bf(v3) << 16);
            *(uint2*)&dst[(mt * 16 + m16) * LP + (w + g * 4) * 16 + q * 4] = u;
        }
    }
}

template<int MT, bool RELU>
__device__ __forceinline__ void layerR1(const unsigned short* src, unsigned short* dst,
                                        const bhalf8 (&bfr)[4],
                                        const float* __restrict__ bias,
                                        int m16, int q, int w) {
    const float4 bb = *(const float4*)&bias[w * 16 + q * 4];
    #pragma unroll
    for (int mt = 0; mt < MT; ++mt) {
        bhalf8 afr[4];
        #pragma unroll
        for (int kc = 0; kc < 4; ++kc)
            afr[kc] = *(const bhalf8*)&src[(mt * 16 + m16) * LP + kc * 32 + q * 8];
        f32x4 acc = {bb.x, bb.y, bb.z, bb.w};
        #pragma unroll
        for (int kc = 0; kc < 4; ++kc)
            acc = __builtin_amdgcn_mfma_f32_16x16x32_bf16(bfr[kc], afr[kc], acc, 0, 0, 0);
        float v0 = acc[0], v1 = acc[1], v2 = acc[2], v3 = acc[3];
        if (RELU) {
            v0 = fmaxf(v0, 0.f); v1 = fmaxf(v1, 0.f);
            v2 = fmaxf(v2, 0.f); v3 = fmaxf(v3, 0.f);
        }
        uint2 u;
        u.x = (unsigned)f2bf(v0) | ((unsigned)f2bf(v1) << 16);
        u.y = (unsigned)f2bf(v2) | ((unsigned)f2bf(v3) << 16);
        *(uint2*)&dst[(mt * 16 + m16) * LP + w * 16 + q * 4] = u;
    }
}

// N=64 final layer -> global fp32 (one float4 store per tile)
template<int MT>
__device__ __forceinline__ void layer_outR(const unsigned short* src,
                                           const bhalf8 (&bfr)[4],
                                           const float* __restrict__ bias,
                                           float* __restrict__ out, int base,
                                           int m16, int q, int w) {
    const float4 bb = *(const float4*)&bias[w * 16 + q * 4];
    #pragma unroll
    for (int mt = 0; mt < MT; ++mt) {
        bhalf8 afr[4];
        #pragma unroll
        for (int kc = 0; kc < 4; ++kc)
            afr[kc] = *(const bhalf8*)&src[(mt * 16 + m16) * LP + kc * 32 + q * 8];
        f32x4 acc = {bb.x, bb.y, bb.z, bb.w};
        #pragma unroll
        for (int kc = 0; kc < 4; ++kc)
            acc = __builtin_amdgcn_mfma_f32_16x16x32_bf16(bfr[kc], afr[kc], acc, 0, 0, 0);
        float4 o;
        o.x = acc[0]; o.y = acc[1]; o.z = acc[2]; o.w = acc[3];
        *(float4*)&out[(size_t)(base + mt * 16 + m16) * 64 + w * 16 + q * 4] = o;
    }
}

// ---------------- main kernels -----------------------------------------------
template<int S, int C>
__global__ __launch_bounds__(256, 2)
void cycle_mfma(const float* __restrict__ edge_rep, const float* __restrict__ cyc,
                const int* __restrict__ e2c,
                const unsigned short* __restrict__ W1T, const float* __restrict__ b1,
                const unsigned short* __restrict__ W2T, const float* __restrict__ b2,
                const unsigned short* __restrict__ WeffT, const float* __restrict__ beff,
                const unsigned short* __restrict__ Wc2T, const float* __restrict__ bc2,
                const unsigned short* __restrict__ Wc3T, const float* __restrict__ bc3,
                float* __restrict__ out) {
    constexpr int R = S * C;
    constexpr int MT = R / 16;
    static_assert(R % 16 == 0, "rows per block must be multiple of 16");
    __shared__ unsigned short bufA[R * LP];
    __shared__ unsigned short bufB[R * LP];

    const int tid = threadIdx.x;
    const int lane = tid & 63;
    const int w = tid >> 6;
    const int m16 = lane & 15;
    const int q = lane >> 4;
    const int base = blockIdx.x * R;

    // preload all layer weights into registers (latency overlaps gather below)
    bhalf8 w1f[2][4], weff[2][4], wc2f[2][4];
    bhalf8 w2f[4], wc3f[4];
    loadW2(w1f, W1T, m16, q, w);
    loadW1(w2f, W2T, m16, q, w);
    loadW2(weff, WeffT, m16, q, w);
    loadW2(wc2f, Wc2T, m16, q, w);
    loadW1(wc3f, Wc3T, m16, q, w);

    // gather: bufA = [cyc | edge_rep[i0]+edge_rep[i1]]  (bf16)
    {
        const float4* cyc4 = (const float4*)cyc + (size_t)base * 16;
        for (int i = tid; i < R * 16; i += 256) {
            int r = i >> 4, c = i & 15;
            store4bf(&bufA[r * LP + c * 4], cyc4[i]);
        }
        const float4* er4 = (const float4*)edge_rep;
        for (int i = tid; i < R * 16; i += 256) {
            int r = i >> 4, c = i & 15;
            int g = base + r;
            int i0 = e2c[2 * g], i1 = e2c[2 * g + 1];
            float4 a = er4[(size_t)i0 * 16 + c];
            float4 b = er4[(size_t)i1 * 16 + c];
            float4 s{a.x + b.x, a.y + b.y, a.z + b.z, a.w + b.w};
            store4bf(&bufA[r * LP + 64 + c * 4], s);
        }
    }
    __syncthreads();

    layerR2<MT, true>(bufA, bufB, w1f, b1, m16, q, w);   // h = relu(in@W1)
    __syncthreads();
    layerR1<MT, true>(bufB, bufA, w2f, b2, m16, q, w);   // x -> bufA cols 0:63
    __syncthreads();

    // per-cycle segment sum broadcast into bufA cols 64:127 (paired columns)
    {
        const int p = tid & 31;                 // column pair (2 cols = u32)
        for (int cc = tid >> 5; cc < C; cc += 8) {
            float sx = 0.f, sy = 0.f;
            #pragma unroll
            for (int j = 0; j < S; ++j) {
                unsigned u = *(const unsigned*)&bufA[(cc * S + j) * LP + 2 * p];
                sx += bf2f((unsigned short)(u & 0xffffu));
                sy += bf2f((unsigned short)(u >> 16));
            }
            unsigned o = (unsigned)f2bf(sx) | ((unsigned)f2bf(sy) << 16);
            #pragma unroll
            for (int j = 0; j < S; ++j)
                *(unsigned*)&bufA[(cc * S + j) * LP + 64 + 2 * p] = o;
        }
    }
    __syncthreads();

    layerR2<MT, true>(bufA, bufB, weff, beff, m16, q, w); // y1
    __syncthreads();
    layerR2<MT, true>(bufB, bufA, wc2f, bc2, m16, q, w);  // y2
    __syncthreads();
    layer_outR<MT>(bufA, wc3f, bc3, out, base, m16, q, w); // out
}

template<int RB>
__global__ __launch_bounds__(256, 3)
void edge_mfma(const float* __restrict__ edge_rep, const float* __restrict__ cycle_out,
               const int* __restrict__ c2e,
               const unsigned short* __restrict__ We1T, const float* __restrict__ be1,
               const unsigned short* __restrict__ We2T, const float* __restrict__ be2,
               float* __restrict__ out) {
    constexpr int MT = RB / 16;
    __shared__ unsigned short bufA[RB * LP];
    __shared__ unsigned short bufB[RB * LP];

    const int tid = threadIdx.x;
    const int lane = tid & 63;
    const int w = tid >> 6;
    const int m16 = lane & 15;
    const int q = lane >> 4;
    const int base = blockIdx.x * RB;

    bhalf8 we1f[2][4], we2f[4];
    loadW2(we1f, We1T, m16, q, w);
    loadW1(we2f, We2T, m16, q, w);

    {
        const float4* er4 = (const float4*)edge_rep + (size_t)base * 16;
        for (int i = tid; i < RB * 16; i += 256) {
            int r = i >> 4, c = i & 15;
            store4bf(&bufA[r * LP + c * 4], er4[i]);
        }
        const float4* co4 = (const float4*)cycle_out;
        for (int i = tid; i < RB * 16; i += 256) {
            int r = i >> 4, c = i & 15;
            int g = base + r;
            int j0 = c2e[4 * g], j1 = c2e[4 * g + 1], j2 = c2e[4 * g + 2], j3 = c2e[4 * g + 3];
            float4 a = co4[(size_t)j0 * 16 + c];
            float4 b = co4[(size_t)j1 * 16 + c];
            float4 cc = co4[(size_t)j2 * 16 + c];
            float4 d = co4[(size_t)j3 * 16 + c];
            float4 s{a.x + b.x + cc.x + d.x, a.y + b.y + cc.y + d.y,
                     a.z + b.z + cc.z + d.z, a.w + b.w + cc.w + d.w};
            store4bf(&bufA[r * LP + 64 + c * 4], s);
        }
    }
    __syncthreads();

    layerR2<MT, true>(bufA, bufB, we1f, be1, m16, q, w);
    __syncthreads();
    layer_outR<MT>(bufB, we2f, be2, out, base, m16, q, w);
}

// ---------------- launch ------------------------------------------------------
extern "C" void kernel_launch(void* const* d_in, const int* in_sizes, int n_in,
                              void* d_out, int out_size, void* d_ws, size_t ws_size,
                              hipStream_t stream) {
    const float* edge_rep = (const float*)d_in[0];
    const float* cyc5     = (const float*)d_in[1];
    const float* cyc6     = (const float*)d_in[2];
    const int*   e2c5     = (const int*)  d_in[3];
    const int*   e2c6     = (const int*)  d_in[4];
    const int*   c2e      = (const int*)  d_in[5];
    const float* W1   = (const float*)d_in[6];
    const float* b1   = (const float*)d_in[7];
    const float* W2   = (const float*)d_in[8];
    const float* b2   = (const float*)d_in[9];
    const float* Wc1  = (const float*)d_in[10];
    const float* bc1  = (const float*)d_in[11];
    const float* Wc2  = (const float*)d_in[12];
    const float* bc2  = (const float*)d_in[13];
    const float* Wc3  = (const float*)d_in[14];
    const float* bc3  = (const float*)d_in[15];
    const float* We1  = (const float*)d_in[16];
    const float* be1  = (const float*)d_in[17];
    const float* We2  = (const float*)d_in[18];
    const float* be2  = (const float*)d_in[19];
    const float* Wid5 = (const float*)d_in[20];
    const float* Wsum5= (const float*)d_in[21];
    const float* bab5 = (const float*)d_in[22];
    const float* Wid6 = (const float*)d_in[23];
    const float* Wsum6= (const float*)d_in[24];
    const float* bab6 = (const float*)d_in[25];

    const int NE     = in_sizes[0] / 64;    // 200000
    const int nrows5 = in_sizes[1] / 64;    // 150000
    const int nrows6 = in_sizes[2] / 64;    // 180000

    // workspace layout (bf16 elements)
    unsigned short* wsp    = (unsigned short*)d_ws;
    unsigned short* W1T    = wsp;                 // 128x128
    unsigned short* W2T    = wsp + 16384;         // 64x128
    unsigned short* WeffT5 = wsp + 24576;         // 128x128
    unsigned short* WeffT6 = wsp + 40960;         // 128x128
    unsigned short* Wc2T   = wsp + 57344;         // 128x128
    unsigned short* Wc3T   = wsp + 73728;         // 64x128
    unsigned short* We1T   = wsp + 81920;         // 128x128
    unsigned short* We2T   = wsp + 98304;         // 64x128
    float* beff5 = (float*)(wsp + 106496);        // 128 fp32
    float* beff6 = (float*)(wsp + 106752);        // 128 fp32

    tcast_all<<<288, 256, 0, stream>>>(W1, W2, Wc2, Wc3, We1, We2,
                                       W1T, W2T, Wc2T, Wc3T, We1T, We2T);
    weff_all<<<258, 128, 0, stream>>>(Wc1, Wid5, Wsum5, Wid6, Wsum6,
                                      bab5, bab6, bc1, WeffT5, WeffT6, beff5, beff6);

    float* out      = (float*)d_out;
    float* out5     = out + (size_t)NE * 64;
    float* out6     = out5 + (size_t)nrows5 * 64;
    const float* cycle_out = out5;

    cycle_mfma<5, 16><<<nrows5 / 80, 256, 0, stream>>>(
        edge_rep, cyc5, e2c5, W1T, b1, W2T, b2, WeffT5, beff5,
        Wc2T, bc2, Wc3T, bc3, out5);
    cycle_mfma<6, 16><<<nrows6 / 96, 256, 0, stream>>>(
        edge_rep, cyc6, e2c6, W1T, b1, W2T, b2, WeffT6, beff6,
        Wc2T, bc2, Wc3T, bc3, out6);
    edge_mfma<64><<<NE / 64, 256, 0, stream>>>(
        edge_rep, cycle_out, c2e, We1T, be1, We2T, be2, out);
}

// Round 3
// 454.256 us; speedup vs baseline: 1.0398x; 1.0398x over previous
//
#include <hip/hip_runtime.h>

// Edge_cycle fused block, bf16-MFMA, round 7.
//   Round 7: BF16 EDGE GATHER. edge_rep is pre-cast to bf16 (25.6MB) in one
//   streaming pass; both cycle kernels gather 128B bf16 rows instead of 256B
//   fp32 rows -- halves random-gather bytes AND cache-line requests (the
//   dominant memory-system load per R1/R2 evidence: time invariant to
//   occupancy/tile/scheduling => service-rate bound on the gather mix).
//   Weights stay in registers (R6, neutral). edge_mfma untouched this round.
// d_out layout: [edge_out NE*64][out5][out6]; cycle_out = d_out + NE*64.

#define LP 136   // LDS row pitch in bf16 units (128+8: 16B-aligned, 2-way-free banks)

typedef __attribute__((ext_vector_type(8))) short bhalf8;
typedef __attribute__((ext_vector_type(4))) float f32x4;

__device__ __forceinline__ unsigned short f2bf(float f) {
    unsigned u = __builtin_bit_cast(unsigned, f);
    u += 0x7fffu + ((u >> 16) & 1u);          // RNE
    return (unsigned short)(u >> 16);
}
__device__ __forceinline__ float bf2f(unsigned short s) {
    unsigned u = ((unsigned)s) << 16;
    return __builtin_bit_cast(float, u);
}
__device__ __forceinline__ float blo(unsigned u) {           // low bf16 of u32 -> f32
    return __builtin_bit_cast(float, u << 16);
}
__device__ __forceinline__ float bhi(unsigned u) {           // high bf16 of u32 -> f32
    return __builtin_bit_cast(float, u & 0xffff0000u);
}
__device__ __forceinline__ void store4bf(unsigned short* p, float4 v) {
    uint2 u;
    u.x = (unsigned)f2bf(v.x) | ((unsigned)f2bf(v.y) << 16);
    u.y = (unsigned)f2bf(v.z) | ((unsigned)f2bf(v.w) << 16);
    *(uint2*)p = u;
}

// ---------------- prep kernels -----------------------------------------------
// blocks 0-63:W1  64-95:W2  96-159:Wc2  160-191:Wc3  192-255:We1  256-287:We2
__global__ void tcast_all(const float* __restrict__ W1,  const float* __restrict__ W2,
                          const float* __restrict__ Wc2, const float* __restrict__ Wc3,
                          const float* __restrict__ We1, const float* __restrict__ We2,
                          unsigned short* W1T, unsigned short* W2T,
                          unsigned short* Wc2T, unsigned short* Wc3T,
                          unsigned short* We1T, unsigned short* We2T) {
    int b = blockIdx.x;
    const float* W; unsigned short* WT; int logN, i0;
    if      (b < 64)  { W = W1;  WT = W1T;  logN = 7; i0 = b; }
    else if (b < 96)  { W = W2;  WT = W2T;  logN = 6; i0 = b - 64; }
    else if (b < 160) { W = Wc2; WT = Wc2T; logN = 7; i0 = b - 96; }
    else if (b < 192) { W = Wc3; WT = Wc3T; logN = 6; i0 = b - 160; }
    else if (b < 256) { W = We1; WT = We1T; logN = 7; i0 = b - 192; }
    else              { W = We2; WT = We2T; logN = 6; i0 = b - 256; }
    int i = i0 * 256 + threadIdx.x;
    int k = i >> logN;
    int n = i & ((1 << logN) - 1);
    WT[n * 128 + k] = f2bf(W[i]);
}

// stream-cast edge_rep (NE*64 f32) -> bf16 rows of 128B
__global__ void cast_edge(const float* __restrict__ er, unsigned short* __restrict__ ebf,
                          int n4) {
    int i = blockIdx.x * 256 + threadIdx.x;
    if (i < n4) {
        float4 v = ((const float4*)er)[i];
        store4bf(&ebf[(size_t)i * 4], v);
    }
}

// blocks 0-127: WeffT5 row k=b; 128-255: WeffT6; 256: beff5; 257: beff6
__global__ void weff_all(const float* __restrict__ Wc1,
                         const float* __restrict__ Wid5, const float* __restrict__ Wsum5,
                         const float* __restrict__ Wid6, const float* __restrict__ Wsum6,
                         const float* __restrict__ bab5, const float* __restrict__ bab6,
                         const float* __restrict__ bc1,
                         unsigned short* WeffT5, unsigned short* WeffT6,
                         float* beff5, float* beff6) {
    int b = blockIdx.x, n = threadIdx.x;
    if (b < 256) {
        int k = b & 127;
        const float* Wid  = (b < 128) ? Wid5  : Wid6;
        const float* Wsum = (b < 128) ? Wsum5 : Wsum6;
        unsigned short* WT = (b < 128) ? WeffT5 : WeffT6;
        const float* Ws = (k < 64) ? (Wid + (size_t)k * 256) : (Wsum + (size_t)(k - 64) * 256);
        float v = Wc1[k * 128 + n];
        for (int j = 0; j < 256; ++j) v = fmaf(Ws[j], Wc1[(128 + j) * 128 + n], v);
        WT[n * 128 + k] = f2bf(v);
    } else {
        const float* bab = (b == 256) ? bab5 : bab6;
        float* beff = (b == 256) ? beff5 : beff6;
        float v = bc1[n];
        for (int j = 0; j < 256; ++j) v = fmaf(bab[j], Wc1[(128 + j) * 128 + n], v);
        beff[n] = v;
    }
}

// ---------------- weight preload into registers -------------------------------
__device__ __forceinline__ void loadW2(bhalf8 (&bfr)[2][4], const unsigned short* __restrict__ WT,
                                       int m16, int q, int w) {
    #pragma unroll
    for (int g = 0; g < 2; ++g) {
        const int ntg = w + g * 4;
        #pragma unroll
        for (int kc = 0; kc < 4; ++kc)
            bfr[g][kc] = *(const bhalf8*)&WT[(size_t)(ntg * 16 + m16) * 128 + kc * 32 + q * 8];
    }
}
__device__ __forceinline__ void loadW1(bhalf8 (&bfr)[4], const unsigned short* __restrict__ WT,
                                       int m16, int q, int w) {
    #pragma unroll
    for (int kc = 0; kc < 4; ++kc)
        bfr[kc] = *(const bhalf8*)&WT[(size_t)(w * 16 + m16) * 128 + kc * 32 + q * 8];
}

// ---------------- MFMA layers: weights from registers, A from LDS -------------
// Swapped-operand form: mfma(bfr, afr) = (x@W)^T fragment; lane holds
// x_row = m16 (+mt*16), n = ntg*16 + q*4 + r  (4 consecutive cols -> packed store).
template<int MT, bool RELU>
__device__ __forceinline__ void layerR2(const unsigned short* src, unsigned short* dst,
                                        const bhalf8 (&bfr)[2][4],
                                        const float* __restrict__ bias,
                                        int m16, int q, int w) {
    float4 bb[2];
    #pragma unroll
    for (int g = 0; g < 2; ++g) bb[g] = *(const float4*)&bias[(w + g * 4) * 16 + q * 4];
    #pragma unroll
    for (int mt = 0; mt < MT; ++mt) {
        bhalf8 afr[4];
        #pragma unroll
        for (int kc = 0; kc < 4; ++kc)
            afr[kc] = *(const bhalf8*)&src[(mt * 16 + m16) * LP + kc * 32 + q * 8];
        #pragma unroll
        for (int g = 0; g < 2; ++g) {
            f32x4 acc = {bb[g].x, bb[g].y, bb[g].z, bb[g].w};
            #pragma unroll
            for (int kc = 0; kc < 4; ++kc)
                acc = __builtin_amdgcn_mfma_f32_16x16x32_bf16(bfr[g][kc], afr[kc], acc, 0, 0, 0);
            float v0 = acc[0], v1 = acc[1], v2 = acc[2], v3 = acc[3];
            if (RELU) {
                v0 = fmaxf(v0, 0.f); v1 = fmaxf(v1, 0.f);
                v2 = fmaxf(v2, 0.f); v3 = fmaxf(v3, 0.f);
            }
            uint2 u;
            u.x = (unsigned)f2bf(v0) | ((unsigned)f2bf(v1) << 16);
            u.y = (unsigned)f2bf(v2) | ((unsigned)f2bf(v3) << 16);
            *(uint2*)&dst[(mt * 16 + m16) * LP + (w + g * 4) * 16 + q * 4] = u;
        }
    }
}

template<int MT, bool RELU>
__device__ __forceinline__ void layerR1(const unsigned short* src, unsigned short* dst,
                                        const bhalf8 (&bfr)[4],
                                        const float* __restrict__ bias,
                                        int m16, int q, int w) {
    const float4 bb = *(const float4*)&bias[w * 16 + q * 4];
    #pragma unroll
    for (int mt = 0; mt < MT; ++mt) {
        bhalf8 afr[4];
        #pragma unroll
        for (int kc = 0; kc < 4; ++kc)
            afr[kc] = *(const bhalf8*)&src[(mt * 16 + m16) * LP + kc * 32 + q * 8];
        f32x4 acc = {bb.x, bb.y, bb.z, bb.w};
        #pragma unroll
        for (int kc = 0; kc < 4; ++kc)
            acc = __builtin_amdgcn_mfma_f32_16x16x32_bf16(bfr[kc], afr[kc], acc, 0, 0, 0);
        float v0 = acc[0], v1 = acc[1], v2 = acc[2], v3 = acc[3];
        if (RELU) {
            v0 = fmaxf(v0, 0.f); v1 = fmaxf(v1, 0.f);
            v2 = fmaxf(v2, 0.f); v3 = fmaxf(v3, 0.f);
        }
        uint2 u;
        u.x = (unsigned)f2bf(v0) | ((unsigned)f2bf(v1) << 16);
        u.y = (unsigned)f2bf(v2) | ((unsigned)f2bf(v3) << 16);
        *(uint2*)&dst[(mt * 16 + m16) * LP + w * 16 + q * 4] = u;
    }
}

// N=64 final layer -> global fp32 (one float4 store per tile)
template<int MT>
__device__ __forceinline__ void layer_outR(const unsigned short* src,
                                           const bhalf8 (&bfr)[4],
                                           const float* __restrict__ bias,
                                           float* __restrict__ out, int base,
                                           int m16, int q, int w) {
    const float4 bb = *(const float4*)&bias[w * 16 + q * 4];
    #pragma unroll
    for (int mt = 0; mt < MT; ++mt) {
        bhalf8 afr[4];
        #pragma unroll
        for (int kc = 0; kc < 4; ++kc)
            afr[kc] = *(const bhalf8*)&src[(mt * 16 + m16) * LP + kc * 32 + q * 8];
        f32x4 acc = {bb.x, bb.y, bb.z, bb.w};
        #pragma unroll
        for (int kc = 0; kc < 4; ++kc)
            acc = __builtin_amdgcn_mfma_f32_16x16x32_bf16(bfr[kc], afr[kc], acc, 0, 0, 0);
        float4 o;
        o.x = acc[0]; o.y = acc[1]; o.z = acc[2]; o.w = acc[3];
        *(float4*)&out[(size_t)(base + mt * 16 + m16) * 64 + w * 16 + q * 4] = o;
    }
}

// ---------------- main kernels -----------------------------------------------
template<int S, int C, bool BF>
__global__ __launch_bounds__(256, 2)
void cycle_mfma(const float* __restrict__ edge_rep,
                const unsigned short* __restrict__ edge_bf,
                const float* __restrict__ cyc,
                const int* __restrict__ e2c,
                const unsigned short* __restrict__ W1T, const float* __restrict__ b1,
                const unsigned short* __restrict__ W2T, const float* __restrict__ b2,
                const unsigned short* __restrict__ WeffT, const float* __restrict__ beff,
                const unsigned short* __restrict__ Wc2T, const float* __restrict__ bc2,
                const unsigned short* __restrict__ Wc3T, const float* __restrict__ bc3,
                float* __restrict__ out) {
    constexpr int R = S * C;
    constexpr int MT = R / 16;
    static_assert(R % 16 == 0, "rows per block must be multiple of 16");
    __shared__ unsigned short bufA[R * LP];
    __shared__ unsigned short bufB[R * LP];

    const int tid = threadIdx.x;
    const int lane = tid & 63;
    const int w = tid >> 6;
    const int m16 = lane & 15;
    const int q = lane >> 4;
    const int base = blockIdx.x * R;

    // preload all layer weights into registers (latency overlaps gather below)
    bhalf8 w1f[2][4], weff[2][4], wc2f[2][4];
    bhalf8 w2f[4], wc3f[4];
    loadW2(w1f, W1T, m16, q, w);
    loadW1(w2f, W2T, m16, q, w);
    loadW2(weff, WeffT, m16, q, w);
    loadW2(wc2f, Wc2T, m16, q, w);
    loadW1(wc3f, Wc3T, m16, q, w);

    // gather: bufA = [cyc | edge_rep[i0]+edge_rep[i1]]  (bf16)
    {
        const float4* cyc4 = (const float4*)cyc + (size_t)base * 16;
        for (int i = tid; i < R * 16; i += 256) {
            int r = i >> 4, c = i & 15;
            store4bf(&bufA[r * LP + c * 4], cyc4[i]);
        }
        if (BF) {
            const uint2* eb2 = (const uint2*)edge_bf;   // 16 x 8B chunks per row
            for (int i = tid; i < R * 16; i += 256) {
                int r = i >> 4, c = i & 15;
                int g = base + r;
                int i0 = e2c[2 * g], i1 = e2c[2 * g + 1];
                uint2 a = eb2[(size_t)i0 * 16 + c];
                uint2 b = eb2[(size_t)i1 * 16 + c];
                float s0 = blo(a.x) + blo(b.x);
                float s1 = bhi(a.x) + bhi(b.x);
                float s2 = blo(a.y) + blo(b.y);
                float s3 = bhi(a.y) + bhi(b.y);
                uint2 o;
                o.x = (unsigned)f2bf(s0) | ((unsigned)f2bf(s1) << 16);
                o.y = (unsigned)f2bf(s2) | ((unsigned)f2bf(s3) << 16);
                *(uint2*)&bufA[r * LP + 64 + c * 4] = o;
            }
        } else {
            const float4* er4 = (const float4*)edge_rep;
            for (int i = tid; i < R * 16; i += 256) {
                int r = i >> 4, c = i & 15;
                int g = base + r;
                int i0 = e2c[2 * g], i1 = e2c[2 * g + 1];
                float4 a = er4[(size_t)i0 * 16 + c];
                float4 b = er4[(size_t)i1 * 16 + c];
                float4 s{a.x + b.x, a.y + b.y, a.z + b.z, a.w + b.w};
                store4bf(&bufA[r * LP + 64 + c * 4], s);
            }
        }
    }
    __syncthreads();

    layerR2<MT, true>(bufA, bufB, w1f, b1, m16, q, w);   // h = relu(in@W1)
    __syncthreads();
    layerR1<MT, true>(bufB, bufA, w2f, b2, m16, q, w);   // x -> bufA cols 0:63
    __syncthreads();

    // per-cycle segment sum broadcast into bufA cols 64:127 (paired columns)
    {
        const int p = tid & 31;                 // column pair (2 cols = u32)
        for (int cc = tid >> 5; cc < C; cc += 8) {
            float sx = 0.f, sy = 0.f;
            #pragma unroll
            for (int j = 0; j < S; ++j) {
                unsigned u = *(const unsigned*)&bufA[(cc * S + j) * LP + 2 * p];
                sx += bf2f((unsigned short)(u & 0xffffu));
                sy += bf2f((unsigned short)(u >> 16));
            }
            unsigned o = (unsigned)f2bf(sx) | ((unsigned)f2bf(sy) << 16);
            #pragma unroll
            for (int j = 0; j < S; ++j)
                *(unsigned*)&bufA[(cc * S + j) * LP + 64 + 2 * p] = o;
        }
    }
    __syncthreads();

    layerR2<MT, true>(bufA, bufB, weff, beff, m16, q, w); // y1
    __syncthreads();
    layerR2<MT, true>(bufB, bufA, wc2f, bc2, m16, q, w);  // y2
    __syncthreads();
    layer_outR<MT>(bufA, wc3f, bc3, out, base, m16, q, w); // out
}

template<int RB>
__global__ __launch_bounds__(256, 3)
void edge_mfma(const float* __restrict__ edge_rep, const float* __restrict__ cycle_out,
               const int* __restrict__ c2e,
               const unsigned short* __restrict__ We1T, const float* __restrict__ be1,
               const unsigned short* __restrict__ We2T, const float* __restrict__ be2,
               float* __restrict__ out) {
    constexpr int MT = RB / 16;
    __shared__ unsigned short bufA[RB * LP];
    __shared__ unsigned short bufB[RB * LP];

    const int tid = threadIdx.x;
    const int lane = tid & 63;
    const int w = tid >> 6;
    const int m16 = lane & 15;
    const int q = lane >> 4;
    const int base = blockIdx.x * RB;

    bhalf8 we1f[2][4], we2f[4];
    loadW2(we1f, We1T, m16, q, w);
    loadW1(we2f, We2T, m16, q, w);

    {
        const float4* er4 = (const float4*)edge_rep + (size_t)base * 16;
        for (int i = tid; i < RB * 16; i += 256) {
            int r = i >> 4, c = i & 15;
            store4bf(&bufA[r * LP + c * 4], er4[i]);
        }
        const float4* co4 = (const float4*)cycle_out;
        for (int i = tid; i < RB * 16; i += 256) {
            int r = i >> 4, c = i & 15;
            int g = base + r;
            int j0 = c2e[4 * g], j1 = c2e[4 * g + 1], j2 = c2e[4 * g + 2], j3 = c2e[4 * g + 3];
            float4 a = co4[(size_t)j0 * 16 + c];
            float4 b = co4[(size_t)j1 * 16 + c];
            float4 cc = co4[(size_t)j2 * 16 + c];
            float4 d = co4[(size_t)j3 * 16 + c];
            float4 s{a.x + b.x + cc.x + d.x, a.y + b.y + cc.y + d.y,
                     a.z + b.z + cc.z + d.z, a.w + b.w + cc.w + d.w};
            store4bf(&bufA[r * LP + 64 + c * 4], s);
        }
    }
    __syncthreads();

    layerR2<MT, true>(bufA, bufB, we1f, be1, m16, q, w);
    __syncthreads();
    layer_outR<MT>(bufB, we2f, be2, out, base, m16, q, w);
}

// ---------------- launch ------------------------------------------------------
extern "C" void kernel_launch(void* const* d_in, const int* in_sizes, int n_in,
                              void* d_out, int out_size, void* d_ws, size_t ws_size,
                              hipStream_t stream) {
    const float* edge_rep = (const float*)d_in[0];
    const float* cyc5     = (const float*)d_in[1];
    const float* cyc6     = (const float*)d_in[2];
    const int*   e2c5     = (const int*)  d_in[3];
    const int*   e2c6     = (const int*)  d_in[4];
    const int*   c2e      = (const int*)  d_in[5];
    const float* W1   = (const float*)d_in[6];
    const float* b1   = (const float*)d_in[7];
    const float* W2   = (const float*)d_in[8];
    const float* b2   = (const float*)d_in[9];
    const float* Wc1  = (const float*)d_in[10];
    const float* bc1  = (const float*)d_in[11];
    const float* Wc2  = (const float*)d_in[12];
    const float* bc2  = (const float*)d_in[13];
    const float* Wc3  = (const float*)d_in[14];
    const float* bc3  = (const float*)d_in[15];
    const float* We1  = (const float*)d_in[16];
    const float* be1  = (const float*)d_in[17];
    const float* We2  = (const float*)d_in[18];
    const float* be2  = (const float*)d_in[19];
    const float* Wid5 = (const float*)d_in[20];
    const float* Wsum5= (const float*)d_in[21];
    const float* bab5 = (const float*)d_in[22];
    const float* Wid6 = (const float*)d_in[23];
    const float* Wsum6= (const float*)d_in[24];
    const float* bab6 = (const float*)d_in[25];

    const int NE     = in_sizes[0] / 64;    // 200000
    const int nrows5 = in_sizes[1] / 64;    // 150000
    const int nrows6 = in_sizes[2] / 64;    // 180000

    // workspace layout (bf16 elements)
    unsigned short* wsp    = (unsigned short*)d_ws;
    unsigned short* W1T    = wsp;                 // 128x128
    unsigned short* W2T    = wsp + 16384;         // 64x128
    unsigned short* WeffT5 = wsp + 24576;         // 128x128
    unsigned short* WeffT6 = wsp + 40960;         // 128x128
    unsigned short* Wc2T   = wsp + 57344;         // 128x128
    unsigned short* Wc3T   = wsp + 73728;         // 64x128
    unsigned short* We1T   = wsp + 81920;         // 128x128
    unsigned short* We2T   = wsp + 98304;         // 64x128
    float* beff5 = (float*)(wsp + 106496);        // 128 fp32
    float* beff6 = (float*)(wsp + 106752);        // 128 fp32
    unsigned short* edge_bf = wsp + 131072;       // NE x 64 bf16 (25.6MB), 256KB-offset
    const bool useBF = ws_size >= (size_t)(131072 + (size_t)NE * 64) * 2;

    tcast_all<<<288, 256, 0, stream>>>(W1, W2, Wc2, Wc3, We1, We2,
                                       W1T, W2T, Wc2T, Wc3T, We1T, We2T);
    weff_all<<<258, 128, 0, stream>>>(Wc1, Wid5, Wsum5, Wid6, Wsum6,
                                      bab5, bab6, bc1, WeffT5, WeffT6, beff5, beff6);
    if (useBF)
        cast_edge<<<(NE * 16 + 255) / 256, 256, 0, stream>>>(edge_rep, edge_bf, NE * 16);

    float* out      = (float*)d_out;
    float* out5     = out + (size_t)NE * 64;
    float* out6     = out5 + (size_t)nrows5 * 64;
    const float* cycle_out = out5;

    if (useBF) {
        cycle_mfma<5, 16, true><<<nrows5 / 80, 256, 0, stream>>>(
            edge_rep, edge_bf, cyc5, e2c5, W1T, b1, W2T, b2, WeffT5, beff5,
            Wc2T, bc2, Wc3T, bc3, out5);
        cycle_mfma<6, 16, true><<<nrows6 / 96, 256, 0, stream>>>(
            edge_rep, edge_bf, cyc6, e2c6, W1T, b1, W2T, b2, WeffT6, beff6,
            Wc2T, bc2, Wc3T, bc3, out6);
    } else {
        cycle_mfma<5, 16, false><<<nrows5 / 80, 256, 0, stream>>>(
            edge_rep, edge_bf, cyc5, e2c5, W1T, b1, W2T, b2, WeffT5, beff5,
            Wc2T, bc2, Wc3T, bc3, out5);
        cycle_mfma<6, 16, false><<<nrows6 / 96, 256, 0, stream>>>(
            edge_rep, edge_bf, cyc6, e2c6, W1T, b1, W2T, b2, WeffT6, beff6,
            Wc2T, bc2, Wc3T, bc3, out6);
    }
    edge_mfma<64><<<NE / 64, 256, 0, stream>>>(
        edge_rep, cycle_out, c2e, We1T, be1, We2T, be2, out);
}

// Round 4
// 447.054 us; speedup vs baseline: 1.0566x; 1.0161x over previous
//
#include <hip/hip_runtime.h>

// Edge_cycle fused block, bf16-MFMA, round 8.
//   Round 8: BF16 GATHER EVERYWHERE. R3 proved the service-rate model: halving
//   random-gather bytes cut c6 by 17% (FETCH 68->46MB). edge_mfma has the
//   worst gather (4 random 256B fp32 rows x 200K). Now: cycle kernels mirror
//   their fp32 output as bf16 into workspace (cyc_bf); edge_mfma gathers 128B
//   bf16 rows (half the random traffic) and streams edge_rep from edge_bf
//   (half the streaming fetch). All gathers use 16B/lane bhalf8 loads.
// d_out layout: [edge_out NE*64][out5][out6]; cycle_out = d_out + NE*64.

#define LP 136   // LDS row pitch in bf16 units (128+8: 16B-aligned, 2-way-free banks)

typedef __attribute__((ext_vector_type(8))) short bhalf8;
typedef __attribute__((ext_vector_type(4))) float f32x4;

__device__ __forceinline__ unsigned short f2bf(float f) {
    unsigned u = __builtin_bit_cast(unsigned, f);
    u += 0x7fffu + ((u >> 16) & 1u);          // RNE
    return (unsigned short)(u >> 16);
}
__device__ __forceinline__ float bf2f(unsigned short s) {
    unsigned u = ((unsigned)s) << 16;
    return __builtin_bit_cast(float, u);
}
__device__ __forceinline__ float blo(unsigned u) {           // low bf16 of u32 -> f32
    return __builtin_bit_cast(float, u << 16);
}
__device__ __forceinline__ float bhi(unsigned u) {           // high bf16 of u32 -> f32
    return __builtin_bit_cast(float, u & 0xffff0000u);
}
__device__ __forceinline__ unsigned pck(float lo, float hi) {
    return (unsigned)f2bf(lo) | ((unsigned)f2bf(hi) << 16);
}
__device__ __forceinline__ void store4bf(unsigned short* p, float4 v) {
    uint2 u;
    u.x = pck(v.x, v.y);
    u.y = pck(v.z, v.w);
    *(uint2*)p = u;
}
__device__ __forceinline__ bhalf8 add2bf(bhalf8 a, bhalf8 b) {
    uint4 ua = __builtin_bit_cast(uint4, a), ub = __builtin_bit_cast(uint4, b);
    uint4 o;
    o.x = pck(blo(ua.x) + blo(ub.x), bhi(ua.x) + bhi(ub.x));
    o.y = pck(blo(ua.y) + blo(ub.y), bhi(ua.y) + bhi(ub.y));
    o.z = pck(blo(ua.z) + blo(ub.z), bhi(ua.z) + bhi(ub.z));
    o.w = pck(blo(ua.w) + blo(ub.w), bhi(ua.w) + bhi(ub.w));
    return __builtin_bit_cast(bhalf8, o);
}
__device__ __forceinline__ bhalf8 add4bf(bhalf8 a, bhalf8 b, bhalf8 c, bhalf8 d) {
    uint4 ua = __builtin_bit_cast(uint4, a), ub = __builtin_bit_cast(uint4, b);
    uint4 uc = __builtin_bit_cast(uint4, c), ud = __builtin_bit_cast(uint4, d);
    uint4 o;
    o.x = pck(blo(ua.x) + blo(ub.x) + blo(uc.x) + blo(ud.x),
              bhi(ua.x) + bhi(ub.x) + bhi(uc.x) + bhi(ud.x));
    o.y = pck(blo(ua.y) + blo(ub.y) + blo(uc.y) + blo(ud.y),
              bhi(ua.y) + bhi(ub.y) + bhi(uc.y) + bhi(ud.y));
    o.z = pck(blo(ua.z) + blo(ub.z) + blo(uc.z) + blo(ud.z),
              bhi(ua.z) + bhi(ub.z) + bhi(uc.z) + bhi(ud.z));
    o.w = pck(blo(ua.w) + blo(ub.w) + blo(uc.w) + blo(ud.w),
              bhi(ua.w) + bhi(ub.w) + bhi(uc.w) + bhi(ud.w));
    return __builtin_bit_cast(bhalf8, o);
}

// ---------------- prep kernels -----------------------------------------------
// blocks 0-63:W1  64-95:W2  96-159:Wc2  160-191:Wc3  192-255:We1  256-287:We2
__global__ void tcast_all(const float* __restrict__ W1,  const float* __restrict__ W2,
                          const float* __restrict__ Wc2, const float* __restrict__ Wc3,
                          const float* __restrict__ We1, const float* __restrict__ We2,
                          unsigned short* W1T, unsigned short* W2T,
                          unsigned short* Wc2T, unsigned short* Wc3T,
                          unsigned short* We1T, unsigned short* We2T) {
    int b = blockIdx.x;
    const float* W; unsigned short* WT; int logN, i0;
    if      (b < 64)  { W = W1;  WT = W1T;  logN = 7; i0 = b; }
    else if (b < 96)  { W = W2;  WT = W2T;  logN = 6; i0 = b - 64; }
    else if (b < 160) { W = Wc2; WT = Wc2T; logN = 7; i0 = b - 96; }
    else if (b < 192) { W = Wc3; WT = Wc3T; logN = 6; i0 = b - 160; }
    else if (b < 256) { W = We1; WT = We1T; logN = 7; i0 = b - 192; }
    else              { W = We2; WT = We2T; logN = 6; i0 = b - 256; }
    int i = i0 * 256 + threadIdx.x;
    int k = i >> logN;
    int n = i & ((1 << logN) - 1);
    WT[n * 128 + k] = f2bf(W[i]);
}

// stream-cast edge_rep (NE*64 f32) -> bf16 rows of 128B
__global__ void cast_edge(const float* __restrict__ er, unsigned short* __restrict__ ebf,
                          int n4) {
    int i = blockIdx.x * 256 + threadIdx.x;
    if (i < n4) {
        float4 v = ((const float4*)er)[i];
        store4bf(&ebf[(size_t)i * 4], v);
    }
}

// blocks 0-127: WeffT5 row k=b; 128-255: WeffT6; 256: beff5; 257: beff6
__global__ void weff_all(const float* __restrict__ Wc1,
                         const float* __restrict__ Wid5, const float* __restrict__ Wsum5,
                         const float* __restrict__ Wid6, const float* __restrict__ Wsum6,
                         const float* __restrict__ bab5, const float* __restrict__ bab6,
                         const float* __restrict__ bc1,
                         unsigned short* WeffT5, unsigned short* WeffT6,
                         float* beff5, float* beff6) {
    int b = blockIdx.x, n = threadIdx.x;
    if (b < 256) {
        int k = b & 127;
        const float* Wid  = (b < 128) ? Wid5  : Wid6;
        const float* Wsum = (b < 128) ? Wsum5 : Wsum6;
        unsigned short* WT = (b < 128) ? WeffT5 : WeffT6;
        const float* Ws = (k < 64) ? (Wid + (size_t)k * 256) : (Wsum + (size_t)(k - 64) * 256);
        float v = Wc1[k * 128 + n];
        for (int j = 0; j < 256; ++j) v = fmaf(Ws[j], Wc1[(128 + j) * 128 + n], v);
        WT[n * 128 + k] = f2bf(v);
    } else {
        const float* bab = (b == 256) ? bab5 : bab6;
        float* beff = (b == 256) ? beff5 : beff6;
        float v = bc1[n];
        for (int j = 0; j < 256; ++j) v = fmaf(bab[j], Wc1[(128 + j) * 128 + n], v);
        beff[n] = v;
    }
}

// ---------------- weight preload into registers -------------------------------
__device__ __forceinline__ void loadW2(bhalf8 (&bfr)[2][4], const unsigned short* __restrict__ WT,
                                       int m16, int q, int w) {
    #pragma unroll
    for (int g = 0; g < 2; ++g) {
        const int ntg = w + g * 4;
        #pragma unroll
        for (int kc = 0; kc < 4; ++kc)
            bfr[g][kc] = *(const bhalf8*)&WT[(size_t)(ntg * 16 + m16) * 128 + kc * 32 + q * 8];
    }
}
__device__ __forceinline__ void loadW1(bhalf8 (&bfr)[4], const unsigned short* __restrict__ WT,
                                       int m16, int q, int w) {
    #pragma unroll
    for (int kc = 0; kc < 4; ++kc)
        bfr[kc] = *(const bhalf8*)&WT[(size_t)(w * 16 + m16) * 128 + kc * 32 + q * 8];
}

// ---------------- MFMA layers: weights from registers, A from LDS -------------
// Swapped-operand form: mfma(bfr, afr) = (x@W)^T fragment; lane holds
// x_row = m16 (+mt*16), n = ntg*16 + q*4 + r  (4 consecutive cols -> packed store).
template<int MT, bool RELU>
__device__ __forceinline__ void layerR2(const unsigned short* src, unsigned short* dst,
                                        const bhalf8 (&bfr)[2][4],
                                        const float* __restrict__ bias,
                                        int m16, int q, int w) {
    float4 bb[2];
    #pragma unroll
    for (int g = 0; g < 2; ++g) bb[g] = *(const float4*)&bias[(w + g * 4) * 16 + q * 4];
    #pragma unroll
    for (int mt = 0; mt < MT; ++mt) {
        bhalf8 afr[4];
        #pragma unroll
        for (int kc = 0; kc < 4; ++kc)
            afr[kc] = *(const bhalf8*)&src[(mt * 16 + m16) * LP + kc * 32 + q * 8];
        #pragma unroll
        for (int g = 0; g < 2; ++g) {
            f32x4 acc = {bb[g].x, bb[g].y, bb[g].z, bb[g].w};
            #pragma unroll
            for (int kc = 0; kc < 4; ++kc)
                acc = __builtin_amdgcn_mfma_f32_16x16x32_bf16(bfr[g][kc], afr[kc], acc, 0, 0, 0);
            float v0 = acc[0], v1 = acc[1], v2 = acc[2], v3 = acc[3];
            if (RELU) {
                v0 = fmaxf(v0, 0.f); v1 = fmaxf(v1, 0.f);
                v2 = fmaxf(v2, 0.f); v3 = fmaxf(v3, 0.f);
            }
            uint2 u;
            u.x = pck(v0, v1);
            u.y = pck(v2, v3);
            *(uint2*)&dst[(mt * 16 + m16) * LP + (w + g * 4) * 16 + q * 4] = u;
        }
    }
}

template<int MT, bool RELU>
__device__ __forceinline__ void layerR1(const unsigned short* src, unsigned short* dst,
                                        const bhalf8 (&bfr)[4],
                                        const float* __restrict__ bias,
                                        int m16, int q, int w) {
    const float4 bb = *(const float4*)&bias[w * 16 + q * 4];
    #pragma unroll
    for (int mt = 0; mt < MT; ++mt) {
        bhalf8 afr[4];
        #pragma unroll
        for (int kc = 0; kc < 4; ++kc)
            afr[kc] = *(const bhalf8*)&src[(mt * 16 + m16) * LP + kc * 32 + q * 8];
        f32x4 acc = {bb.x, bb.y, bb.z, bb.w};
        #pragma unroll
        for (int kc = 0; kc < 4; ++kc)
            acc = __builtin_amdgcn_mfma_f32_16x16x32_bf16(bfr[kc], afr[kc], acc, 0, 0, 0);
        float v0 = acc[0], v1 = acc[1], v2 = acc[2], v3 = acc[3];
        if (RELU) {
            v0 = fmaxf(v0, 0.f); v1 = fmaxf(v1, 0.f);
            v2 = fmaxf(v2, 0.f); v3 = fmaxf(v3, 0.f);
        }
        uint2 u;
        u.x = pck(v0, v1);
        u.y = pck(v2, v3);
        *(uint2*)&dst[(mt * 16 + m16) * LP + w * 16 + q * 4] = u;
    }
}

// N=64 final layer -> global fp32 (one float4 store per tile) + optional bf16 mirror
template<int MT, bool CB>
__device__ __forceinline__ void layer_outR(const unsigned short* src,
                                           const bhalf8 (&bfr)[4],
                                           const float* __restrict__ bias,
                                           float* __restrict__ out,
                                           unsigned short* __restrict__ out_bf,
                                           int base, int m16, int q, int w) {
    const float4 bb = *(const float4*)&bias[w * 16 + q * 4];
    #pragma unroll
    for (int mt = 0; mt < MT; ++mt) {
        bhalf8 afr[4];
        #pragma unroll
        for (int kc = 0; kc < 4; ++kc)
            afr[kc] = *(const bhalf8*)&src[(mt * 16 + m16) * LP + kc * 32 + q * 8];
        f32x4 acc = {bb.x, bb.y, bb.z, bb.w};
        #pragma unroll
        for (int kc = 0; kc < 4; ++kc)
            acc = __builtin_amdgcn_mfma_f32_16x16x32_bf16(bfr[kc], afr[kc], acc, 0, 0, 0);
        float4 o;
        o.x = acc[0]; o.y = acc[1]; o.z = acc[2]; o.w = acc[3];
        const size_t row = (size_t)(base + mt * 16 + m16);
        *(float4*)&out[row * 64 + w * 16 + q * 4] = o;
        if (CB) {
            uint2 u;
            u.x = pck(o.x, o.y);
            u.y = pck(o.z, o.w);
            *(uint2*)&out_bf[row * 64 + w * 16 + q * 4] = u;
        }
    }
}

// ---------------- main kernels -----------------------------------------------
template<int S, int C, bool BF, bool CB>
__global__ __launch_bounds__(256, 2)
void cycle_mfma(const float* __restrict__ edge_rep,
                const unsigned short* __restrict__ edge_bf,
                const float* __restrict__ cyc,
                const int* __restrict__ e2c,
                const unsigned short* __restrict__ W1T, const float* __restrict__ b1,
                const unsigned short* __restrict__ W2T, const float* __restrict__ b2,
                const unsigned short* __restrict__ WeffT, const float* __restrict__ beff,
                const unsigned short* __restrict__ Wc2T, const float* __restrict__ bc2,
                const unsigned short* __restrict__ Wc3T, const float* __restrict__ bc3,
                float* __restrict__ out, unsigned short* __restrict__ out_bf) {
    constexpr int R = S * C;
    constexpr int MT = R / 16;
    static_assert(R % 16 == 0, "rows per block must be multiple of 16");
    __shared__ unsigned short bufA[R * LP];
    __shared__ unsigned short bufB[R * LP];

    const int tid = threadIdx.x;
    const int lane = tid & 63;
    const int w = tid >> 6;
    const int m16 = lane & 15;
    const int q = lane >> 4;
    const int base = blockIdx.x * R;

    // preload all layer weights into registers (latency overlaps gather below)
    bhalf8 w1f[2][4], weff[2][4], wc2f[2][4];
    bhalf8 w2f[4], wc3f[4];
    loadW2(w1f, W1T, m16, q, w);
    loadW1(w2f, W2T, m16, q, w);
    loadW2(weff, WeffT, m16, q, w);
    loadW2(wc2f, Wc2T, m16, q, w);
    loadW1(wc3f, Wc3T, m16, q, w);

    // gather: bufA = [cyc | edge_rep[i0]+edge_rep[i1]]  (bf16)
    {
        const float4* cyc4 = (const float4*)cyc + (size_t)base * 16;
        for (int i = tid; i < R * 16; i += 256) {
            int r = i >> 4, c = i & 15;
            store4bf(&bufA[r * LP + c * 4], cyc4[i]);
        }
        if (BF) {
            const bhalf8* eb8 = (const bhalf8*)edge_bf;   // 8 x 16B chunks per row
            for (int i = tid; i < R * 8; i += 256) {
                int r = i >> 3, c = i & 7;
                int g = base + r;
                int i0 = e2c[2 * g], i1 = e2c[2 * g + 1];
                bhalf8 a = eb8[(size_t)i0 * 8 + c];
                bhalf8 b = eb8[(size_t)i1 * 8 + c];
                *(bhalf8*)&bufA[r * LP + 64 + c * 8] = add2bf(a, b);
            }
        } else {
            const float4* er4 = (const float4*)edge_rep;
            for (int i = tid; i < R * 16; i += 256) {
                int r = i >> 4, c = i & 15;
                int g = base + r;
                int i0 = e2c[2 * g], i1 = e2c[2 * g + 1];
                float4 a = er4[(size_t)i0 * 16 + c];
                float4 b = er4[(size_t)i1 * 16 + c];
                float4 s{a.x + b.x, a.y + b.y, a.z + b.z, a.w + b.w};
                store4bf(&bufA[r * LP + 64 + c * 4], s);
            }
        }
    }
    __syncthreads();

    layerR2<MT, true>(bufA, bufB, w1f, b1, m16, q, w);   // h = relu(in@W1)
    __syncthreads();
    layerR1<MT, true>(bufB, bufA, w2f, b2, m16, q, w);   // x -> bufA cols 0:63
    __syncthreads();

    // per-cycle segment sum broadcast into bufA cols 64:127 (paired columns)
    {
        const int p = tid & 31;                 // column pair (2 cols = u32)
        for (int cc = tid >> 5; cc < C; cc += 8) {
            float sx = 0.f, sy = 0.f;
            #pragma unroll
            for (int j = 0; j < S; ++j) {
                unsigned u = *(const unsigned*)&bufA[(cc * S + j) * LP + 2 * p];
                sx += bf2f((unsigned short)(u & 0xffffu));
                sy += bf2f((unsigned short)(u >> 16));
            }
            unsigned o = (unsigned)f2bf(sx) | ((unsigned)f2bf(sy) << 16);
            #pragma unroll
            for (int j = 0; j < S; ++j)
                *(unsigned*)&bufA[(cc * S + j) * LP + 64 + 2 * p] = o;
        }
    }
    __syncthreads();

    layerR2<MT, true>(bufA, bufB, weff, beff, m16, q, w); // y1
    __syncthreads();
    layerR2<MT, true>(bufB, bufA, wc2f, bc2, m16, q, w);  // y2
    __syncthreads();
    layer_outR<MT, CB>(bufA, wc3f, bc3, out, out_bf, base, m16, q, w); // out
}

template<int RB, bool CB>
__global__ __launch_bounds__(256, 3)
void edge_mfma(const float* __restrict__ edge_rep,
               const unsigned short* __restrict__ edge_bf,
               const unsigned short* __restrict__ cyc_bf,
               const float* __restrict__ cycle_out,
               const int* __restrict__ c2e,
               const unsigned short* __restrict__ We1T, const float* __restrict__ be1,
               const unsigned short* __restrict__ We2T, const float* __restrict__ be2,
               float* __restrict__ out) {
    constexpr int MT = RB / 16;
    __shared__ unsigned short bufA[RB * LP];
    __shared__ unsigned short bufB[RB * LP];

    const int tid = threadIdx.x;
    const int lane = tid & 63;
    const int w = tid >> 6;
    const int m16 = lane & 15;
    const int q = lane >> 4;
    const int base = blockIdx.x * RB;

    bhalf8 we1f[2][4], we2f[4];
    loadW2(we1f, We1T, m16, q, w);
    loadW1(we2f, We2T, m16, q, w);

    if (CB) {
        // streaming: edge_bf rows straight into LDS (no cvt)
        const bhalf8* eb8 = (const bhalf8*)edge_bf;
        for (int i = tid; i < RB * 8; i += 256) {
            int r = i >> 3, c = i & 7;
            *(bhalf8*)&bufA[r * LP + c * 8] = eb8[(size_t)(base + r) * 8 + c];
        }
        // gather: 4 random 128B bf16 rows from cyc_bf
        const bhalf8* cb8 = (const bhalf8*)cyc_bf;
        for (int i = tid; i < RB * 8; i += 256) {
            int r = i >> 3, c = i & 7;
            int g = base + r;
            int j0 = c2e[4 * g], j1 = c2e[4 * g + 1], j2 = c2e[4 * g + 2], j3 = c2e[4 * g + 3];
            bhalf8 a = cb8[(size_t)j0 * 8 + c];
            bhalf8 b = cb8[(size_t)j1 * 8 + c];
            bhalf8 cc = cb8[(size_t)j2 * 8 + c];
            bhalf8 d = cb8[(size_t)j3 * 8 + c];
            *(bhalf8*)&bufA[r * LP + 64 + c * 8] = add4bf(a, b, cc, d);
        }
    } else {
        const float4* er4 = (const float4*)edge_rep + (size_t)base * 16;
        for (int i = tid; i < RB * 16; i += 256) {
            int r = i >> 4, c = i & 15;
            store4bf(&bufA[r * LP + c * 4], er4[i]);
        }
        const float4* co4 = (const float4*)cycle_out;
        for (int i = tid; i < RB * 16; i += 256) {
            int r = i >> 4, c = i & 15;
            int g = base + r;
            int j0 = c2e[4 * g], j1 = c2e[4 * g + 1], j2 = c2e[4 * g + 2], j3 = c2e[4 * g + 3];
            float4 a = co4[(size_t)j0 * 16 + c];
            float4 b = co4[(size_t)j1 * 16 + c];
            float4 cc = co4[(size_t)j2 * 16 + c];
            float4 d = co4[(size_t)j3 * 16 + c];
            float4 s{a.x + b.x + cc.x + d.x, a.y + b.y + cc.y + d.y,
                     a.z + b.z + cc.z + d.z, a.w + b.w + cc.w + d.w};
            store4bf(&bufA[r * LP + 64 + c * 4], s);
        }
    }
    __syncthreads();

    layerR2<MT, true>(bufA, bufB, we1f, be1, m16, q, w);
    __syncthreads();
    layer_outR<MT, false>(bufB, we2f, be2, out, nullptr, base, m16, q, w);
}

// ---------------- launch ------------------------------------------------------
extern "C" void kernel_launch(void* const* d_in, const int* in_sizes, int n_in,
                              void* d_out, int out_size, void* d_ws, size_t ws_size,
                              hipStream_t stream) {
    const float* edge_rep = (const float*)d_in[0];
    const float* cyc5     = (const float*)d_in[1];
    const float* cyc6     = (const float*)d_in[2];
    const int*   e2c5     = (const int*)  d_in[3];
    const int*   e2c6     = (const int*)  d_in[4];
    const int*   c2e      = (const int*)  d_in[5];
    const float* W1   = (const float*)d_in[6];
    const float* b1   = (const float*)d_in[7];
    const float* W2   = (const float*)d_in[8];
    const float* b2   = (const float*)d_in[9];
    const float* Wc1  = (const float*)d_in[10];
    const float* bc1  = (const float*)d_in[11];
    const float* Wc2  = (const float*)d_in[12];
    const float* bc2  = (const float*)d_in[13];
    const float* Wc3  = (const float*)d_in[14];
    const float* bc3  = (const float*)d_in[15];
    const float* We1  = (const float*)d_in[16];
    const float* be1  = (const float*)d_in[17];
    const float* We2  = (const float*)d_in[18];
    const float* be2  = (const float*)d_in[19];
    const float* Wid5 = (const float*)d_in[20];
    const float* Wsum5= (const float*)d_in[21];
    const float* bab5 = (const float*)d_in[22];
    const float* Wid6 = (const float*)d_in[23];
    const float* Wsum6= (const float*)d_in[24];
    const float* bab6 = (const float*)d_in[25];

    const int NE     = in_sizes[0] / 64;    // 200000
    const int nrows5 = in_sizes[1] / 64;    // 150000
    const int nrows6 = in_sizes[2] / 64;    // 180000

    // workspace layout (bf16 elements)
    unsigned short* wsp    = (unsigned short*)d_ws;
    unsigned short* W1T    = wsp;                 // 128x128
    unsigned short* W2T    = wsp + 16384;         // 64x128
    unsigned short* WeffT5 = wsp + 24576;         // 128x128
    unsigned short* WeffT6 = wsp + 40960;         // 128x128
    unsigned short* Wc2T   = wsp + 57344;         // 128x128
    unsigned short* Wc3T   = wsp + 73728;         // 64x128
    unsigned short* We1T   = wsp + 81920;         // 128x128
    unsigned short* We2T   = wsp + 98304;         // 64x128
    float* beff5 = (float*)(wsp + 106496);        // 128 fp32
    float* beff6 = (float*)(wsp + 106752);        // 128 fp32
    unsigned short* edge_bf = wsp + 131072;       // NE x 64 bf16 (25.6MB)
    unsigned short* cyc_bf  = edge_bf + (size_t)NE * 64;  // (nrows5+nrows6) x 64 bf16 (42.2MB)
    const size_t need_bf = (size_t)(131072 + (size_t)NE * 64) * 2;
    const size_t need_cb = need_bf + (size_t)(nrows5 + nrows6) * 64 * 2;
    const bool useBF = ws_size >= need_bf;
    const bool useCB = ws_size >= need_cb;

    tcast_all<<<288, 256, 0, stream>>>(W1, W2, Wc2, Wc3, We1, We2,
                                       W1T, W2T, Wc2T, Wc3T, We1T, We2T);
    weff_all<<<258, 128, 0, stream>>>(Wc1, Wid5, Wsum5, Wid6, Wsum6,
                                      bab5, bab6, bc1, WeffT5, WeffT6, beff5, beff6);
    if (useBF)
        cast_edge<<<(NE * 16 + 255) / 256, 256, 0, stream>>>(edge_rep, edge_bf, NE * 16);

    float* out      = (float*)d_out;
    float* out5     = out + (size_t)NE * 64;
    float* out6     = out5 + (size_t)nrows5 * 64;
    const float* cycle_out = out5;

    if (useCB) {
        cycle_mfma<5, 16, true, true><<<nrows5 / 80, 256, 0, stream>>>(
            edge_rep, edge_bf, cyc5, e2c5, W1T, b1, W2T, b2, WeffT5, beff5,
            Wc2T, bc2, Wc3T, bc3, out5, cyc_bf);
        cycle_mfma<6, 16, true, true><<<nrows6 / 96, 256, 0, stream>>>(
            edge_rep, edge_bf, cyc6, e2c6, W1T, b1, W2T, b2, WeffT6, beff6,
            Wc2T, bc2, Wc3T, bc3, out6, cyc_bf + (size_t)nrows5 * 64);
        edge_mfma<64, true><<<NE / 64, 256, 0, stream>>>(
            edge_rep, edge_bf, cyc_bf, cycle_out, c2e, We1T, be1, We2T, be2, out);
    } else if (useBF) {
        cycle_mfma<5, 16, true, false><<<nrows5 / 80, 256, 0, stream>>>(
            edge_rep, edge_bf, cyc5, e2c5, W1T, b1, W2T, b2, WeffT5, beff5,
            Wc2T, bc2, Wc3T, bc3, out5, nullptr);
        cycle_mfma<6, 16, true, false><<<nrows6 / 96, 256, 0, stream>>>(
            edge_rep, edge_bf, cyc6, e2c6, W1T, b1, W2T, b2, WeffT6, beff6,
            Wc2T, bc2, Wc3T, bc3, out6, nullptr);
        edge_mfma<64, false><<<NE / 64, 256, 0, stream>>>(
            edge_rep, edge_bf, nullptr, cycle_out, c2e, We1T, be1, We2T, be2, out);
    } else {
        cycle_mfma<5, 16, false, false><<<nrows5 / 80, 256, 0, stream>>>(
            edge_rep, edge_bf, cyc5, e2c5, W1T, b1, W2T, b2, WeffT5, beff5,
            Wc2T, bc2, Wc3T, bc3, out5, nullptr);
        cycle_mfma<6, 16, false, false><<<nrows6 / 96, 256, 0, stream>>>(
            edge_rep, edge_bf, cyc6, e2c6, W1T, b1, W2T, b2, WeffT6, beff6,
            Wc2T, bc2, Wc3T, bc3, out6, nullptr);
        edge_mfma<64, false><<<NE / 64, 256, 0, stream>>>(
            edge_rep, edge_bf, nullptr, cycle_out, c2e, We1T, be1, We2T, be2, out);
    }
}